// Round 4
// baseline (226.366 us; speedup 1.0000x reference)
//
#include <hip/hip_runtime.h>

// Problem constants
#define B_ 2
#define T_ 2048
#define C_ 1024
#define H_ 16
#define D_ 64

typedef __bf16 bf16x8 __attribute__((ext_vector_type(8)));
typedef float f32x4 __attribute__((ext_vector_type(4)));

__device__ __forceinline__ unsigned short f2bf(float f) {
  unsigned u = __float_as_uint(f);
  unsigned r = (u + 0x7fffu + ((u >> 16) & 1u)) >> 16;  // RN-even
  return (unsigned short)r;
}

__device__ __forceinline__ float exp2_hw(float x) {
  float r;
  asm("v_exp_f32 %0, %1" : "=v"(r) : "v"(x));
  return r;
}

// ---------------- fused fp32 -> bf16 conversion (all three tensors) --------
#define NX 1048576   // x float4 count
#define NWA 786432   // w_attn float4 count
#define NWP 262144   // w_proj float4 count
__global__ __launch_bounds__(256) void convert_all(
    const float* __restrict__ x, const float* __restrict__ wa,
    const float* __restrict__ wp, unsigned short* __restrict__ xb,
    unsigned short* __restrict__ wab, unsigned short* __restrict__ wpb) {
  int i = blockIdx.x * 256 + threadIdx.x;
  const float* s; unsigned short* d; int j;
  if (i < NX)            { s = x;  d = xb;  j = i; }
  else if (i < NX + NWA) { s = wa; d = wab; j = i - NX; }
  else                   { s = wp; d = wpb; j = i - NX - NWA; }
  float4 v = ((const float4*)s)[j];
  ushort4 u;
  u.x = f2bf(v.x); u.y = f2bf(v.y); u.z = f2bf(v.z); u.w = f2bf(v.w);
  ((ushort4*)d)[j] = u;
}

// ---------------- bf16 MFMA GEMM: C[m,n] = sum_k A[m,k]*B[n,k] + bias[n] ----
// 128x128 tile, 768/256 blocks -> 3/1.5 per CU (grid matters more than the
// 256^2 8-phase schedule at this shape: R3 measured 256^2 = 44.9us vs ~40us).
// LDS rows XOR-swizzled at 16B atoms: physical = logical^(row&7).
// mode 0: fp32 row-major out. mode 1: bf16 Q(x0.125*log2e)/K [B,H,T,D], V [B,H,D,T].
__global__ __launch_bounds__(256) void gemm_bt(
    const unsigned short* __restrict__ A,   // [M][K] bf16
    const unsigned short* __restrict__ Bm,  // [N][K] bf16
    const float* __restrict__ bias,         // [N] fp32
    int M, int N, int K, int mode,
    float* __restrict__ outf,
    unsigned short* __restrict__ qb,
    unsigned short* __restrict__ kb,
    unsigned short* __restrict__ vb) {
  __shared__ unsigned short As[128 * 64];
  __shared__ unsigned short Bs[128 * 64];

  const int tid  = threadIdx.x;
  const int lane = tid & 63;
  const int wave = tid >> 6;
  const int quad = lane >> 4;
  const int l16  = lane & 15;
  const int q4   = quad * 4;

  const int bm = blockIdx.y * 128;
  const int bn = blockIdx.x * 128;
  const int wm = (wave >> 1) * 64;
  const int wn = (wave & 1) * 64;

  f32x4 acc[4][4] = {};

  const int srow8 = lane >> 3;                       // row within 8-row group
  const int scol  = ((lane & 7) ^ srow8) * 8;        // swizzled source column
  const int srow  = wave * 8 + srow8;

  for (int k0 = 0; k0 < K; k0 += 64) {
#pragma unroll
    for (int c = 0; c < 4; ++c) {
      const int r = c * 32 + srow;
      const unsigned short* ga = A  + (size_t)(bm + r) * K + (k0 + scol);
      const unsigned short* gb = Bm + (size_t)(bn + r) * K + (k0 + scol);
      unsigned short* la = &As[(c * 32 + wave * 8) * 64];
      unsigned short* lb = &Bs[(c * 32 + wave * 8) * 64];
      __builtin_amdgcn_global_load_lds(
          (__attribute__((address_space(1))) unsigned int*)ga,
          (__attribute__((address_space(3))) unsigned int*)la, 16, 0, 0);
      __builtin_amdgcn_global_load_lds(
          (__attribute__((address_space(1))) unsigned int*)gb,
          (__attribute__((address_space(3))) unsigned int*)lb, 16, 0, 0);
    }
    __syncthreads();
#pragma unroll
    for (int ks = 0; ks < 2; ++ks) {
      bf16x8 af[4], bfr[4];
#pragma unroll
      for (int i = 0; i < 4; ++i)
        af[i] = *(const bf16x8*)&As[(wm + i * 16 + l16) * 64 +
                                    (((ks * 4 + quad) ^ (l16 & 7)) * 8)];
#pragma unroll
      for (int j = 0; j < 4; ++j)
        bfr[j] = *(const bf16x8*)&Bs[(wn + j * 16 + l16) * 64 +
                                     (((ks * 4 + quad) ^ (l16 & 7)) * 8)];
#pragma unroll
      for (int i = 0; i < 4; ++i)
#pragma unroll
        for (int j = 0; j < 4; ++j)
          acc[i][j] = __builtin_amdgcn_mfma_f32_16x16x32_bf16(af[i], bfr[j], acc[i][j], 0, 0, 0);
    }
    __syncthreads();
  }

#pragma unroll
  for (int j = 0; j < 4; ++j) {
    const int gn = bn + wn + j * 16 + l16;
    const float bv = bias[gn];
    if (mode == 0) {
#pragma unroll
      for (int i = 0; i < 4; ++i)
#pragma unroll
        for (int r = 0; r < 4; ++r) {
          const int gm = bm + wm + i * 16 + q4 + r;
          outf[(size_t)gm * N + gn] = acc[i][j][r] + bv;
        }
    } else {
      const int which = gn >> 10;      // 0=q 1=k 2=v
      const int cc = gn & 1023;
      const int h = cc >> 6, d = cc & 63;
      if (which == 2) {
        // V transposed [b,h,d,t]: pack 4 consecutive t into one ushort4
#pragma unroll
        for (int i = 0; i < 4; ++i) {
          const int gm0 = bm + wm + i * 16 + q4;
          const int b = gm0 >> 11, t0 = gm0 & 2047;
          ushort4 u;
          u.x = f2bf(acc[i][j][0] + bv);
          u.y = f2bf(acc[i][j][1] + bv);
          u.z = f2bf(acc[i][j][2] + bv);
          u.w = f2bf(acc[i][j][3] + bv);
          *(ushort4*)&vb[(((size_t)(b * H_ + h) * D_) + d) * T_ + t0] = u;
        }
      } else {
        // Q gets 1/sqrt(64) * log2(e) folded in -> softmax uses bare v_exp_f32
        const float sc = (which == 0) ? 0.18033688011112042f : 1.0f;
        unsigned short* dst = (which == 0) ? qb : kb;
#pragma unroll
        for (int i = 0; i < 4; ++i)
#pragma unroll
          for (int r = 0; r < 4; ++r) {
            const int gm = bm + wm + i * 16 + q4 + r;
            const int b = gm >> 11, t = gm & 2047;
            dst[(((size_t)(b * H_ + h) * T_) + t) * D_ + d] = f2bf((acc[i][j][r] + bv) * sc);
          }
      }
    }
  }
}

// ---------------- MFMA causal flash attention, key-split, barrier-free -----
// K/V per head = 256KB each -> L2/L3 resident. No LDS staging, NO BARRIERS:
// each wave loads K/V fragments directly from global (L2-hit) and runs its
// causal tile range independently. LDS holds only the per-wave P buffer
// (wave-private, same-wave lgkmcnt ordering -> no sync needed). V fragment
// loads issued before the softmax VALU chain to hide their latency.
// Fixed-max softmax (log2e folded into Q -> bare v_exp_f32); key-split work
// item w in [0,40) per bh; partials combined by attn_combine.
__global__ __launch_bounds__(256, 2) void attn_mfma(
    const unsigned short* __restrict__ Qb,
    const unsigned short* __restrict__ Kb,   // [b,h,t,d]
    const unsigned short* __restrict__ Vtg,  // [b,h,d,t]
    unsigned short* __restrict__ Yb,
    unsigned short* __restrict__ op,         // partial O  [1280][128][64] bf16
    float* __restrict__ lp) {                // partial l  [1280][128] fp32
  __shared__ unsigned short Pw[4][32 * 64];  // per-wave [q][key] (swizzled)

  const int tid  = threadIdx.x;
  const int lane = tid & 63;
  const int wave = tid >> 6;
  const int quad = lane >> 4;
  const int l16  = lane & 15;
  const int q4   = quad * 4;
  const int sw   = (l16 & 7);                // swizzle key

  const int id = blockIdx.x;                 // 0..1279
  const int bh = id / 40;
  const int w  = id - bh * 40;
  int qt, chunk, nsplits;
  if (w < 4)       { qt = w;                 chunk = 0;            nsplits = 1; }
  else if (w < 12) { qt = 4 + ((w - 4) >> 1); chunk = (w - 4) & 1;  nsplits = 2; }
  else if (w < 24) { qt = 8 + (w - 12) / 3;  chunk = (w - 12) % 3; nsplits = 3; }
  else             { qt = 12 + ((w - 24) >> 2); chunk = (w - 24) & 3; nsplits = 4; }

  const int tiles_total = 2 * qt + 2;
  const int tpc = (tiles_total + nsplits - 1) / nsplits;
  const int t0 = chunk * tpc;
  const int t1 = min(t0 + tpc, tiles_total);

  const int b = bh >> 4, h = bh & 15;
  const size_t base = (size_t)bh * T_ * D_;
  const int wq = qt * 128 + wave * 32;       // wave's first global q row
  const int wmax = min(t1, (wq + 95) >> 6);  // wave's causal tile bound

  // Q fragments (B-operand layout), loaded once from global
  bf16x8 qf[2][2];
#pragma unroll
  for (int nt = 0; nt < 2; ++nt)
#pragma unroll
    for (int ks = 0; ks < 2; ++ks)
      qf[nt][ks] = *(const bf16x8*)(Qb + base + (size_t)(wq + nt * 16 + l16) * 64 +
                                    ks * 32 + quad * 8);

  f32x4 o[4][2] = {};                        // O^T tiles: [d-tile][q-tile]
  float l2[2] = {0.f, 0.f};

  for (int kt = t0; kt < wmax; ++kt) {
    const int kt0 = kt * 64;

    // ---- direct global fragment loads (L2-hit; no staging, no barriers) ----
    bf16x8 kf[2][4], vf[2][4];
#pragma unroll
    for (int ks = 0; ks < 2; ++ks)
#pragma unroll
      for (int mt = 0; mt < 4; ++mt)
        kf[ks][mt] = *(const bf16x8*)(Kb + base +
                                      (size_t)(kt0 + mt * 16 + l16) * 64 +
                                      ks * 32 + quad * 8);
#pragma unroll
    for (int ks = 0; ks < 2; ++ks)
#pragma unroll
      for (int dt = 0; dt < 4; ++dt)
        vf[ks][dt] = *(const bf16x8*)(Vtg + base +
                                      (size_t)(dt * 16 + l16) * T_ +
                                      kt0 + ks * 32 + quad * 8);

    // ---- S^T = K Q^T ----
    f32x4 s[4][2] = {};
#pragma unroll
    for (int ks = 0; ks < 2; ++ks) {
      __builtin_amdgcn_s_setprio(1);
#pragma unroll
      for (int mt = 0; mt < 4; ++mt)
#pragma unroll
        for (int nt = 0; nt < 2; ++nt)
          s[mt][nt] = __builtin_amdgcn_mfma_f32_16x16x32_bf16(kf[ks][mt], qf[nt][ks],
                                                              s[mt][nt], 0, 0, 0);
      __builtin_amdgcn_s_setprio(0);
    }

    // ---- causal mask (boundary tiles only) ----
    if (kt0 + 63 > wq) {
#pragma unroll
      for (int mt = 0; mt < 4; ++mt)
#pragma unroll
        for (int nt = 0; nt < 2; ++nt)
#pragma unroll
          for (int r = 0; r < 4; ++r)
            if (kt0 + mt * 16 + q4 + r > wq + nt * 16 + l16) s[mt][nt][r] = -1e30f;
    }

    // ---- fixed-max softmax: p = 2^s (log2e pre-folded into Q) ----
#pragma unroll
    for (int nt = 0; nt < 2; ++nt) {
      float ps = 0.f;
#pragma unroll
      for (int mt = 0; mt < 4; ++mt) {
        float p0 = exp2_hw(s[mt][nt][0]);
        float p1 = exp2_hw(s[mt][nt][1]);
        float p2 = exp2_hw(s[mt][nt][2]);
        float p3 = exp2_hw(s[mt][nt][3]);
        ps += (p0 + p1) + (p2 + p3);
        unsigned lo, hi;
        asm("v_cvt_pk_bf16_f32 %0, %1, %2" : "=v"(lo) : "v"(p0), "v"(p1));
        asm("v_cvt_pk_bf16_f32 %0, %1, %2" : "=v"(hi) : "v"(p2), "v"(p3));
        uint2 pk; pk.x = lo; pk.y = hi;
        const int atom = (2 * mt + (quad >> 1)) ^ sw;   // swizzled P atom
        *(uint2*)&Pw[wave][(nt * 16 + l16) * 64 + atom * 8 + (quad & 1) * 4] = pk;
      }
      l2[nt] += ps;
    }

    // ---- O^T += V^T P^T ----
#pragma unroll
    for (int ks = 0; ks < 2; ++ks) {
      bf16x8 pf[2];
#pragma unroll
      for (int nt = 0; nt < 2; ++nt)
        pf[nt] = *(const bf16x8*)&Pw[wave][(nt * 16 + l16) * 64 +
                                          (((ks * 4 + quad) ^ sw) * 8)];
      __builtin_amdgcn_s_setprio(1);
#pragma unroll
      for (int dt = 0; dt < 4; ++dt)
#pragma unroll
        for (int nt = 0; nt < 2; ++nt)
          o[dt][nt] = __builtin_amdgcn_mfma_f32_16x16x32_bf16(vf[ks][dt], pf[nt],
                                                              o[dt][nt], 0, 0, 0);
      __builtin_amdgcn_s_setprio(0);
    }
  }

  // ---- epilogue ----
#pragma unroll
  for (int nt = 0; nt < 2; ++nt) {
    float l = l2[nt];
    l += __shfl_xor(l, 16);
    l += __shfl_xor(l, 32);
    const int qloc = wave * 32 + nt * 16 + l16;
    if (nsplits == 1) {
      const float inv = 1.f / (l + 1e-6f);   // reference denom eps
      const int q = qt * 128 + qloc;
#pragma unroll
      for (int dt = 0; dt < 4; ++dt) {
        ushort4 u;
        u.x = f2bf(o[dt][nt][0] * inv);
        u.y = f2bf(o[dt][nt][1] * inv);
        u.z = f2bf(o[dt][nt][2] * inv);
        u.w = f2bf(o[dt][nt][3] * inv);
        *(ushort4*)&Yb[((size_t)(b * T_ + q)) * C_ + h * 64 + dt * 16 + q4] = u;
      }
    } else {
      // partial write: slot = id (w already = prefix[qt]+chunk)
      if (quad == 0) lp[(size_t)id * 128 + qloc] = l;
#pragma unroll
      for (int dt = 0; dt < 4; ++dt) {
        ushort4 u;
        u.x = f2bf(o[dt][nt][0]);
        u.y = f2bf(o[dt][nt][1]);
        u.z = f2bf(o[dt][nt][2]);
        u.w = f2bf(o[dt][nt][3]);
        *(ushort4*)&op[(size_t)id * 8192 + (size_t)qloc * 64 + dt * 16 + q4] = u;
      }
    }
  }
}

// ---------------- combine split-K partials -> yb ---------------------------
__global__ __launch_bounds__(256) void attn_combine(
    const unsigned short* __restrict__ op, const float* __restrict__ lp,
    unsigned short* __restrict__ Yb) {
  const int cb = blockIdx.x;                 // 0..383
  const int bh = cb / 12;
  const int qi = cb - bh * 12;
  const int qt = 4 + qi;
  int nsplits, pfx;
  if (qt < 8)       { nsplits = 2; pfx = 4 + 2 * (qt - 4); }
  else if (qt < 12) { nsplits = 3; pfx = 12 + 3 * (qt - 8); }
  else              { nsplits = 4; pfx = 24 + 4 * (qt - 12); }
  const int slot0 = bh * 40 + pfx;

  const int t = threadIdx.x;
  const int qloc = t >> 1;
  const int d0 = (t & 1) * 32;

  float l = 1e-6f;
  float acc[32];
#pragma unroll
  for (int i = 0; i < 32; ++i) acc[i] = 0.f;
  for (int s = 0; s < nsplits; ++s) {
    l += lp[(size_t)(slot0 + s) * 128 + qloc];
    const uint4* src = (const uint4*)(op + (size_t)(slot0 + s) * 8192 +
                                      (size_t)qloc * 64 + d0);
#pragma unroll
    for (int c = 0; c < 4; ++c) {
      uint4 v = src[c];
      acc[c*8+0] += __uint_as_float(v.x << 16);
      acc[c*8+1] += __uint_as_float(v.x & 0xffff0000u);
      acc[c*8+2] += __uint_as_float(v.y << 16);
      acc[c*8+3] += __uint_as_float(v.y & 0xffff0000u);
      acc[c*8+4] += __uint_as_float(v.z << 16);
      acc[c*8+5] += __uint_as_float(v.z & 0xffff0000u);
      acc[c*8+6] += __uint_as_float(v.w << 16);
      acc[c*8+7] += __uint_as_float(v.w & 0xffff0000u);
    }
  }
  const float inv = 1.f / l;
  const int b = bh >> 4, h = bh & 15;
  const int q = qt * 128 + qloc;
  uint4* dst = (uint4*)(Yb + ((size_t)(b * T_ + q)) * C_ + h * 64 + d0);
#pragma unroll
  for (int c = 0; c < 4; ++c) {
    uint4 v;
    v.x = (unsigned)f2bf(acc[c*8+0] * inv) | ((unsigned)f2bf(acc[c*8+1] * inv) << 16);
    v.y = (unsigned)f2bf(acc[c*8+2] * inv) | ((unsigned)f2bf(acc[c*8+3] * inv) << 16);
    v.z = (unsigned)f2bf(acc[c*8+4] * inv) | ((unsigned)f2bf(acc[c*8+5] * inv) << 16);
    v.w = (unsigned)f2bf(acc[c*8+6] * inv) | ((unsigned)f2bf(acc[c*8+7] * inv) << 16);
    dst[c] = v;
  }
}

extern "C" void kernel_launch(void* const* d_in, const int* in_sizes, int n_in,
                              void* d_out, int out_size, void* d_ws, size_t ws_size,
                              hipStream_t stream) {
  const float* x      = (const float*)d_in[0];
  const float* w_attn = (const float*)d_in[1];
  const float* b_attn = (const float*)d_in[2];
  const float* w_proj = (const float*)d_in[3];
  const float* b_proj = (const float*)d_in[4];
  float* out = (float*)d_out;

  char* ws = (char*)d_ws;
  unsigned short* xb  = (unsigned short*)ws;  ws += (size_t)4096 * 1024 * 2;
  unsigned short* wab = (unsigned short*)ws;  ws += (size_t)3072 * 1024 * 2;
  unsigned short* wpb = (unsigned short*)ws;  ws += (size_t)1024 * 1024 * 2;
  unsigned short* qb  = (unsigned short*)ws;  ws += (size_t)B_ * H_ * T_ * D_ * 2;
  unsigned short* kb  = (unsigned short*)ws;  ws += (size_t)B_ * H_ * T_ * D_ * 2;
  unsigned short* vb  = (unsigned short*)ws;  ws += (size_t)B_ * H_ * T_ * D_ * 2;  // [b,h,d,t]
  unsigned short* yb  = (unsigned short*)ws;  ws += (size_t)4096 * 1024 * 2;
  unsigned short* op  = (unsigned short*)ws;  ws += (size_t)1280 * 128 * 64 * 2;    // partial O
  float*          lp  = (float*)ws;           ws += (size_t)1280 * 128 * 4;         // partial l
  (void)ws_size; (void)in_sizes; (void)n_in; (void)out_size;

  convert_all<<<8192, 256, 0, stream>>>(x, w_attn, w_proj, xb, wab, wpb);

  // QKV: [4096,1024] @ [3072,1024]^T + b_attn -> bf16 Q(scaled)/K [B,H,T,D], V [B,H,D,T]
  gemm_bt<<<dim3(24, 32), 256, 0, stream>>>(xb, wab, b_attn, 4096, 3072, 1024, 1,
                                            nullptr, qb, kb, vb);
  // barrier-free key-split MFMA causal flash attention
  attn_mfma<<<1280, 256, 0, stream>>>(qb, kb, vb, yb, op, lp);
  attn_combine<<<384, 256, 0, stream>>>(op, lp, yb);
  // proj: [4096,1024] @ [1024,1024]^T + b_proj -> fp32 out
  gemm_bt<<<dim3(8, 32), 256, 0, stream>>>(yb, wpb, b_proj, 4096, 1024, 1024, 0,
                                           out, nullptr, nullptr, nullptr);
}

// Round 5
// 179.441 us; speedup vs baseline: 1.2615x; 1.2615x over previous
//
#include <hip/hip_runtime.h>

// Problem constants
#define B_ 2
#define T_ 2048
#define C_ 1024
#define H_ 16
#define D_ 64

typedef __bf16 bf16x8 __attribute__((ext_vector_type(8)));
typedef float f32x4 __attribute__((ext_vector_type(4)));

__device__ __forceinline__ unsigned short f2bf(float f) {
  unsigned u = __float_as_uint(f);
  unsigned r = (u + 0x7fffu + ((u >> 16) & 1u)) >> 16;  // RN-even
  return (unsigned short)r;
}

__device__ __forceinline__ float exp2_hw(float x) {
  float r;
  asm("v_exp_f32 %0, %1" : "=v"(r) : "v"(x));
  return r;
}

// ---------------- fused fp32 -> bf16 conversion (all three tensors) --------
#define NX 1048576   // x float4 count
#define NWA 786432   // w_attn float4 count
#define NWP 262144   // w_proj float4 count
__global__ __launch_bounds__(256) void convert_all(
    const float* __restrict__ x, const float* __restrict__ wa,
    const float* __restrict__ wp, unsigned short* __restrict__ xb,
    unsigned short* __restrict__ wab, unsigned short* __restrict__ wpb) {
  int i = blockIdx.x * 256 + threadIdx.x;
  const float* s; unsigned short* d; int j;
  if (i < NX)            { s = x;  d = xb;  j = i; }
  else if (i < NX + NWA) { s = wa; d = wab; j = i - NX; }
  else                   { s = wp; d = wpb; j = i - NX - NWA; }
  float4 v = ((const float4*)s)[j];
  ushort4 u;
  u.x = f2bf(v.x); u.y = f2bf(v.y); u.z = f2bf(v.z); u.w = f2bf(v.w);
  ((ushort4*)d)[j] = u;
}

// ---------------- bf16 MFMA GEMM: C[m,n] = sum_k A[m,k]*B[n,k] + bias[n] ----
// 128x128 tile (R3 measured: 256^2 8-phase loses at this grid size).
// LDS rows XOR-swizzled at 16B atoms: physical = logical^(row&7).
// mode 0: fp32 row-major out. mode 1: bf16 Q(x0.125*log2e)/K [B,H,T,D], V [B,H,D,T].
__global__ __launch_bounds__(256) void gemm_bt(
    const unsigned short* __restrict__ A,   // [M][K] bf16
    const unsigned short* __restrict__ Bm,  // [N][K] bf16
    const float* __restrict__ bias,         // [N] fp32
    int M, int N, int K, int mode,
    float* __restrict__ outf,
    unsigned short* __restrict__ qb,
    unsigned short* __restrict__ kb,
    unsigned short* __restrict__ vb) {
  __shared__ unsigned short As[128 * 64];
  __shared__ unsigned short Bs[128 * 64];

  const int tid  = threadIdx.x;
  const int lane = tid & 63;
  const int wave = tid >> 6;
  const int quad = lane >> 4;
  const int l16  = lane & 15;
  const int q4   = quad * 4;

  const int bm = blockIdx.y * 128;
  const int bn = blockIdx.x * 128;
  const int wm = (wave >> 1) * 64;
  const int wn = (wave & 1) * 64;

  f32x4 acc[4][4] = {};

  const int srow8 = lane >> 3;                       // row within 8-row group
  const int scol  = ((lane & 7) ^ srow8) * 8;        // swizzled source column
  const int srow  = wave * 8 + srow8;

  for (int k0 = 0; k0 < K; k0 += 64) {
#pragma unroll
    for (int c = 0; c < 4; ++c) {
      const int r = c * 32 + srow;
      const unsigned short* ga = A  + (size_t)(bm + r) * K + (k0 + scol);
      const unsigned short* gb = Bm + (size_t)(bn + r) * K + (k0 + scol);
      unsigned short* la = &As[(c * 32 + wave * 8) * 64];
      unsigned short* lb = &Bs[(c * 32 + wave * 8) * 64];
      __builtin_amdgcn_global_load_lds(
          (__attribute__((address_space(1))) unsigned int*)ga,
          (__attribute__((address_space(3))) unsigned int*)la, 16, 0, 0);
      __builtin_amdgcn_global_load_lds(
          (__attribute__((address_space(1))) unsigned int*)gb,
          (__attribute__((address_space(3))) unsigned int*)lb, 16, 0, 0);
    }
    __syncthreads();
#pragma unroll
    for (int ks = 0; ks < 2; ++ks) {
      bf16x8 af[4], bfr[4];
#pragma unroll
      for (int i = 0; i < 4; ++i)
        af[i] = *(const bf16x8*)&As[(wm + i * 16 + l16) * 64 +
                                    (((ks * 4 + quad) ^ (l16 & 7)) * 8)];
#pragma unroll
      for (int j = 0; j < 4; ++j)
        bfr[j] = *(const bf16x8*)&Bs[(wn + j * 16 + l16) * 64 +
                                     (((ks * 4 + quad) ^ (l16 & 7)) * 8)];
#pragma unroll
      for (int i = 0; i < 4; ++i)
#pragma unroll
        for (int j = 0; j < 4; ++j)
          acc[i][j] = __builtin_amdgcn_mfma_f32_16x16x32_bf16(af[i], bfr[j], acc[i][j], 0, 0, 0);
    }
    __syncthreads();
  }

#pragma unroll
  for (int j = 0; j < 4; ++j) {
    const int gn = bn + wn + j * 16 + l16;
    const float bv = bias[gn];
    if (mode == 0) {
#pragma unroll
      for (int i = 0; i < 4; ++i)
#pragma unroll
        for (int r = 0; r < 4; ++r) {
          const int gm = bm + wm + i * 16 + q4 + r;
          outf[(size_t)gm * N + gn] = acc[i][j][r] + bv;
        }
    } else {
      const int which = gn >> 10;      // 0=q 1=k 2=v
      const int cc = gn & 1023;
      const int h = cc >> 6, d = cc & 63;
      if (which == 2) {
        // V transposed [b,h,d,t]: pack 4 consecutive t into one ushort4
#pragma unroll
        for (int i = 0; i < 4; ++i) {
          const int gm0 = bm + wm + i * 16 + q4;
          const int b = gm0 >> 11, t0 = gm0 & 2047;
          ushort4 u;
          u.x = f2bf(acc[i][j][0] + bv);
          u.y = f2bf(acc[i][j][1] + bv);
          u.z = f2bf(acc[i][j][2] + bv);
          u.w = f2bf(acc[i][j][3] + bv);
          *(ushort4*)&vb[(((size_t)(b * H_ + h) * D_) + d) * T_ + t0] = u;
        }
      } else {
        // Q gets 1/sqrt(64) * log2(e) folded in -> softmax uses bare v_exp_f32
        const float sc = (which == 0) ? 0.18033688011112042f : 1.0f;
        unsigned short* dst = (which == 0) ? qb : kb;
#pragma unroll
        for (int i = 0; i < 4; ++i)
#pragma unroll
          for (int r = 0; r < 4; ++r) {
            const int gm = bm + wm + i * 16 + q4 + r;
            const int b = gm >> 11, t = gm & 2047;
            dst[(((size_t)(b * H_ + h) * T_) + t) * D_ + d] = f2bf((acc[i][j][r] + bv) * sc);
          }
      }
    }
  }
}

// ---------------- MFMA causal flash attention, key-split -------------------
// R1 structure (LDS dbuf K/V, one barrier/tile, fixed-max softmax with log2e
// folded into Q, cvt_pk P-pack, setprio) + XCD-locality grid encoding:
// id = w*32 + bh, so all 40 blocks sharing one head's K/V (512KB, L2-fit)
// have the same id%8 -> same XCD -> K/V stays in that XCD's 4MB L2
// (4 heads x 512KB = 2MB per XCD). R4 lesson: LDS staging is load-bearing
// (removing it: 41.6 -> 86us, MfmaUtil 15 -> 7.7%).
__global__ __launch_bounds__(256, 2) void attn_mfma(
    const unsigned short* __restrict__ Qb,
    const unsigned short* __restrict__ Kb,   // [b,h,t,d]
    const unsigned short* __restrict__ Vtg,  // [b,h,d,t]
    unsigned short* __restrict__ Yb,
    unsigned short* __restrict__ op,         // partial O  [1280][128][64] bf16
    float* __restrict__ lp) {                // partial l  [1280][128] fp32
  __shared__ unsigned short Ks[2][64 * 64];  // [key][dim]   (swizzled)
  __shared__ unsigned short Vt[2][64 * 64];  // [dim][key]   (swizzled)
  __shared__ unsigned short Pw[4][32 * 64];  // per-wave [q][key] (swizzled)

  const int tid  = threadIdx.x;
  const int lane = tid & 63;
  const int wave = tid >> 6;
  const int quad = lane >> 4;
  const int l16  = lane & 15;
  const int q4   = quad * 4;
  const int sw   = (l16 & 7);                // swizzle key

  const int id = blockIdx.x;                 // 0..1279 = w*32 + bh
  const int bh = id & 31;                    // same bh -> same id%8 -> same XCD
  const int w  = id >> 5;                    // work item in [0,40)
  int qt, chunk, nsplits;
  if (w < 4)       { qt = w;                 chunk = 0;            nsplits = 1; }
  else if (w < 12) { qt = 4 + ((w - 4) >> 1); chunk = (w - 4) & 1;  nsplits = 2; }
  else if (w < 24) { qt = 8 + (w - 12) / 3;  chunk = (w - 12) % 3; nsplits = 3; }
  else             { qt = 12 + ((w - 24) >> 2); chunk = (w - 24) & 3; nsplits = 4; }

  const int tiles_total = 2 * qt + 2;
  const int tpc = (tiles_total + nsplits - 1) / nsplits;
  const int t0 = chunk * tpc;
  const int t1 = min(t0 + tpc, tiles_total);

  const int b = bh >> 4, h = bh & 15;
  const size_t base = (size_t)bh * T_ * D_;
  const int wq = qt * 128 + wave * 32;       // wave's first global q row
  const int wt1 = min(t1, (wq + 95) >> 6);   // wave's causal tile bound

  // Q fragments (B-operand layout), loaded once from global
  bf16x8 qf[2][2];
#pragma unroll
  for (int nt = 0; nt < 2; ++nt)
#pragma unroll
    for (int ks = 0; ks < 2; ++ks)
      qf[nt][ks] = *(const bf16x8*)(Qb + base + (size_t)(wq + nt * 16 + l16) * 64 +
                                    ks * 32 + quad * 8);

  f32x4 o[4][2] = {};                        // O^T tiles: [d-tile][q-tile]
  float l2[2] = {0.f, 0.f};

  const int srow8 = lane >> 3;
  const int satom = ((lane & 7) ^ srow8) * 8;  // swizzled source column

#define STAGE_KV(KT, BI)                                                       \
  do {                                                                         \
    const int kt0s = (KT) * 64;                                                \
    _Pragma("unroll")                                                          \
    for (int c = 0; c < 2; ++c) {                                              \
      const int row = wave * 16 + c * 8 + srow8;                               \
      const unsigned short* gk = Kb + base + (size_t)(kt0s + row) * 64 + satom;\
      const unsigned short* gv = Vtg + base + (size_t)row * T_ + kt0s + satom; \
      unsigned short* lk = &Ks[BI][(wave * 16 + c * 8) * 64];                  \
      unsigned short* lv = &Vt[BI][(wave * 16 + c * 8) * 64];                  \
      __builtin_amdgcn_global_load_lds(                                        \
          (__attribute__((address_space(1))) unsigned int*)gk,                 \
          (__attribute__((address_space(3))) unsigned int*)lk, 16, 0, 0);      \
      __builtin_amdgcn_global_load_lds(                                        \
          (__attribute__((address_space(1))) unsigned int*)gv,                 \
          (__attribute__((address_space(3))) unsigned int*)lv, 16, 0, 0);      \
    }                                                                          \
  } while (0)

  // prologue: stage first tile into buffer 0
  STAGE_KV(t0, 0);
  int cur = 0;

  for (int kt = t0; kt < t1; ++kt) {
    const int kt0 = kt * 64;
    __syncthreads();                         // buf[cur] loads drained (implicit vmcnt0)
    if (kt + 1 < t1) STAGE_KV(kt + 1, cur ^ 1);  // prefetch next tile under compute

    if (kt < wt1) {                          // wave-uniform causal guard
      // ---- S^T = K Q^T ----
      f32x4 s[4][2] = {};
#pragma unroll
      for (int ks = 0; ks < 2; ++ks) {
        bf16x8 kf[4];
#pragma unroll
        for (int mt = 0; mt < 4; ++mt)
          kf[mt] = *(const bf16x8*)&Ks[cur][(mt * 16 + l16) * 64 +
                                           (((ks * 4 + quad) ^ sw) * 8)];
        __builtin_amdgcn_s_setprio(1);
#pragma unroll
        for (int mt = 0; mt < 4; ++mt)
#pragma unroll
          for (int nt = 0; nt < 2; ++nt)
            s[mt][nt] = __builtin_amdgcn_mfma_f32_16x16x32_bf16(kf[mt], qf[nt][ks],
                                                                s[mt][nt], 0, 0, 0);
        __builtin_amdgcn_s_setprio(0);
      }
      // ---- causal mask (boundary tiles only) ----
      if (kt0 + 63 > wq) {
#pragma unroll
        for (int mt = 0; mt < 4; ++mt)
#pragma unroll
          for (int nt = 0; nt < 2; ++nt)
#pragma unroll
            for (int r = 0; r < 4; ++r)
              if (kt0 + mt * 16 + q4 + r > wq + nt * 16 + l16) s[mt][nt][r] = -1e30f;
      }
      // ---- fixed-max softmax: p = 2^s (log2e pre-folded into Q) ----
#pragma unroll
      for (int nt = 0; nt < 2; ++nt) {
        float ps = 0.f;
#pragma unroll
        for (int mt = 0; mt < 4; ++mt) {
          float p0 = exp2_hw(s[mt][nt][0]);
          float p1 = exp2_hw(s[mt][nt][1]);
          float p2 = exp2_hw(s[mt][nt][2]);
          float p3 = exp2_hw(s[mt][nt][3]);
          ps += (p0 + p1) + (p2 + p3);
          unsigned lo, hi;
          asm("v_cvt_pk_bf16_f32 %0, %1, %2" : "=v"(lo) : "v"(p0), "v"(p1));
          asm("v_cvt_pk_bf16_f32 %0, %1, %2" : "=v"(hi) : "v"(p2), "v"(p3));
          uint2 pk; pk.x = lo; pk.y = hi;
          const int atom = (2 * mt + (quad >> 1)) ^ sw;   // swizzled P atom
          *(uint2*)&Pw[wave][(nt * 16 + l16) * 64 + atom * 8 + (quad & 1) * 4] = pk;
        }
        l2[nt] += ps;
      }
      // ---- O^T += V^T P^T ----
#pragma unroll
      for (int ks = 0; ks < 2; ++ks) {
        bf16x8 vf[4], pf[2];
#pragma unroll
        for (int dt = 0; dt < 4; ++dt)
          vf[dt] = *(const bf16x8*)&Vt[cur][(dt * 16 + l16) * 64 +
                                           (((ks * 4 + quad) ^ sw) * 8)];
#pragma unroll
        for (int nt = 0; nt < 2; ++nt)
          pf[nt] = *(const bf16x8*)&Pw[wave][(nt * 16 + l16) * 64 +
                                            (((ks * 4 + quad) ^ sw) * 8)];
        __builtin_amdgcn_s_setprio(1);
#pragma unroll
        for (int dt = 0; dt < 4; ++dt)
#pragma unroll
          for (int nt = 0; nt < 2; ++nt)
            o[dt][nt] = __builtin_amdgcn_mfma_f32_16x16x32_bf16(vf[ks == 0 ? dt : dt], pf[nt],
                                                                o[dt][nt], 0, 0, 0);
        __builtin_amdgcn_s_setprio(0);
      }
    }
    cur ^= 1;
  }
#undef STAGE_KV

  // ---- epilogue ----
#pragma unroll
  for (int nt = 0; nt < 2; ++nt) {
    float l = l2[nt];
    l += __shfl_xor(l, 16);
    l += __shfl_xor(l, 32);
    const int qloc = wave * 32 + nt * 16 + l16;
    if (nsplits == 1) {
      const float inv = 1.f / (l + 1e-6f);   // reference denom eps
      const int q = qt * 128 + qloc;
#pragma unroll
      for (int dt = 0; dt < 4; ++dt) {
        ushort4 u;
        u.x = f2bf(o[dt][nt][0] * inv);
        u.y = f2bf(o[dt][nt][1] * inv);
        u.z = f2bf(o[dt][nt][2] * inv);
        u.w = f2bf(o[dt][nt][3] * inv);
        *(ushort4*)&Yb[((size_t)(b * T_ + q)) * C_ + h * 64 + dt * 16 + q4] = u;
      }
    } else {
      // partial write: slot = id = w*32 + bh
      if (quad == 0) lp[(size_t)id * 128 + qloc] = l;
#pragma unroll
      for (int dt = 0; dt < 4; ++dt) {
        ushort4 u;
        u.x = f2bf(o[dt][nt][0]);
        u.y = f2bf(o[dt][nt][1]);
        u.z = f2bf(o[dt][nt][2]);
        u.w = f2bf(o[dt][nt][3]);
        *(ushort4*)&op[(size_t)id * 8192 + (size_t)qloc * 64 + dt * 16 + q4] = u;
      }
    }
  }
}

// ---------------- combine split-K partials -> yb ---------------------------
// Slot layout matches attn's id = w*32 + bh encoding: slot(w,bh) = w*32 + bh.
__global__ __launch_bounds__(256) void attn_combine(
    const unsigned short* __restrict__ op, const float* __restrict__ lp,
    unsigned short* __restrict__ Yb) {
  const int cb = blockIdx.x;                 // 0..383
  const int bh = cb / 12;
  const int qi = cb - bh * 12;
  const int qt = 4 + qi;
  int nsplits, pfx;
  if (qt < 8)       { nsplits = 2; pfx = 4 + 2 * (qt - 4); }
  else if (qt < 12) { nsplits = 3; pfx = 12 + 3 * (qt - 8); }
  else              { nsplits = 4; pfx = 24 + 4 * (qt - 12); }

  const int t = threadIdx.x;
  const int qloc = t >> 1;
  const int d0 = (t & 1) * 32;

  float l = 1e-6f;
  float acc[32];
#pragma unroll
  for (int i = 0; i < 32; ++i) acc[i] = 0.f;
  for (int s = 0; s < nsplits; ++s) {
    const int slot = (pfx + s) * 32 + bh;
    l += lp[(size_t)slot * 128 + qloc];
    const uint4* src = (const uint4*)(op + (size_t)slot * 8192 +
                                      (size_t)qloc * 64 + d0);
#pragma unroll
    for (int c = 0; c < 4; ++c) {
      uint4 v = src[c];
      acc[c*8+0] += __uint_as_float(v.x << 16);
      acc[c*8+1] += __uint_as_float(v.x & 0xffff0000u);
      acc[c*8+2] += __uint_as_float(v.y << 16);
      acc[c*8+3] += __uint_as_float(v.y & 0xffff0000u);
      acc[c*8+4] += __uint_as_float(v.z << 16);
      acc[c*8+5] += __uint_as_float(v.z & 0xffff0000u);
      acc[c*8+6] += __uint_as_float(v.w << 16);
      acc[c*8+7] += __uint_as_float(v.w & 0xffff0000u);
    }
  }
  const float inv = 1.f / l;
  const int b = bh >> 4, h = bh & 15;
  const int q = qt * 128 + qloc;
  uint4* dst = (uint4*)(Yb + ((size_t)(b * T_ + q)) * C_ + h * 64 + d0);
#pragma unroll
  for (int c = 0; c < 4; ++c) {
    uint4 v;
    v.x = (unsigned)f2bf(acc[c*8+0] * inv) | ((unsigned)f2bf(acc[c*8+1] * inv) << 16);
    v.y = (unsigned)f2bf(acc[c*8+2] * inv) | ((unsigned)f2bf(acc[c*8+3] * inv) << 16);
    v.z = (unsigned)f2bf(acc[c*8+4] * inv) | ((unsigned)f2bf(acc[c*8+5] * inv) << 16);
    v.w = (unsigned)f2bf(acc[c*8+6] * inv) | ((unsigned)f2bf(acc[c*8+7] * inv) << 16);
    dst[c] = v;
  }
}

extern "C" void kernel_launch(void* const* d_in, const int* in_sizes, int n_in,
                              void* d_out, int out_size, void* d_ws, size_t ws_size,
                              hipStream_t stream) {
  const float* x      = (const float*)d_in[0];
  const float* w_attn = (const float*)d_in[1];
  const float* b_attn = (const float*)d_in[2];
  const float* w_proj = (const float*)d_in[3];
  const float* b_proj = (const float*)d_in[4];
  float* out = (float*)d_out;

  char* ws = (char*)d_ws;
  unsigned short* xb  = (unsigned short*)ws;  ws += (size_t)4096 * 1024 * 2;
  unsigned short* wab = (unsigned short*)ws;  ws += (size_t)3072 * 1024 * 2;
  unsigned short* wpb = (unsigned short*)ws;  ws += (size_t)1024 * 1024 * 2;
  unsigned short* qb  = (unsigned short*)ws;  ws += (size_t)B_ * H_ * T_ * D_ * 2;
  unsigned short* kb  = (unsigned short*)ws;  ws += (size_t)B_ * H_ * T_ * D_ * 2;
  unsigned short* vb  = (unsigned short*)ws;  ws += (size_t)B_ * H_ * T_ * D_ * 2;  // [b,h,d,t]
  unsigned short* yb  = (unsigned short*)ws;  ws += (size_t)4096 * 1024 * 2;
  unsigned short* op  = (unsigned short*)ws;  ws += (size_t)1280 * 128 * 64 * 2;    // partial O
  float*          lp  = (float*)ws;           ws += (size_t)1280 * 128 * 4;         // partial l
  (void)ws_size; (void)in_sizes; (void)n_in; (void)out_size;

  convert_all<<<8192, 256, 0, stream>>>(x, w_attn, w_proj, xb, wab, wpb);

  // QKV: [4096,1024] @ [3072,1024]^T + b_attn -> bf16 Q(scaled)/K [B,H,T,D], V [B,H,D,T]
  gemm_bt<<<dim3(24, 32), 256, 0, stream>>>(xb, wab, b_attn, 4096, 3072, 1024, 1,
                                            nullptr, qb, kb, vb);
  // key-split MFMA causal flash attention (XCD-local bh grouping)
  attn_mfma<<<1280, 256, 0, stream>>>(qb, kb, vb, yb, op, lp);
  attn_combine<<<384, 256, 0, stream>>>(op, lp, yb);
  // proj: [4096,1024] @ [1024,1024]^T + b_proj -> fp32 out
  gemm_bt<<<dim3(8, 32), 256, 0, stream>>>(yb, wpb, b_proj, 4096, 1024, 1024, 0,
                                           out, nullptr, nullptr, nullptr);
}

// Round 6
// 168.907 us; speedup vs baseline: 1.3402x; 1.0624x over previous
//
#include <hip/hip_runtime.h>

// Problem constants
#define B_ 2
#define T_ 2048
#define C_ 1024
#define H_ 16
#define D_ 64

typedef __bf16 bf16x8 __attribute__((ext_vector_type(8)));
typedef float f32x4 __attribute__((ext_vector_type(4)));

__device__ __forceinline__ unsigned short f2bf(float f) {
  unsigned u = __float_as_uint(f);
  unsigned r = (u + 0x7fffu + ((u >> 16) & 1u)) >> 16;  // RN-even
  return (unsigned short)r;
}

__device__ __forceinline__ float exp2_hw(float x) {
  float r;
  asm("v_exp_f32 %0, %1" : "=v"(r) : "v"(x));
  return r;
}

// ---------------- fused fp32 -> bf16 conversion (all three tensors) --------
#define NX 1048576   // x float4 count
#define NWA 786432   // w_attn float4 count
#define NWP 262144   // w_proj float4 count
__global__ __launch_bounds__(256) void convert_all(
    const float* __restrict__ x, const float* __restrict__ wa,
    const float* __restrict__ wp, unsigned short* __restrict__ xb,
    unsigned short* __restrict__ wab, unsigned short* __restrict__ wpb) {
  int i = blockIdx.x * 256 + threadIdx.x;
  const float* s; unsigned short* d; int j;
  if (i < NX)            { s = x;  d = xb;  j = i; }
  else if (i < NX + NWA) { s = wa; d = wab; j = i - NX; }
  else                   { s = wp; d = wpb; j = i - NX - NWA; }
  float4 v = ((const float4*)s)[j];
  ushort4 u;
  u.x = f2bf(v.x); u.y = f2bf(v.y); u.z = f2bf(v.z); u.w = f2bf(v.w);
  ((ushort4*)d)[j] = u;
}

// ---------------- bf16 MFMA GEMM: C[m,n] = sum_k A[m,k]*B[n,k] + bias[n] ----
// 128x128 tile, QKV: 768 blocks = 3/CU. LDS rows XOR-swizzled at 16B atoms:
// physical = logical^(row&7).
// mode 0: fp32 row-major out. mode 1: bf16 Q(x0.125*log2e)/K [B,H,T,D], V [B,H,D,T].
__global__ __launch_bounds__(256) void gemm_bt(
    const unsigned short* __restrict__ A,   // [M][K] bf16
    const unsigned short* __restrict__ Bm,  // [N][K] bf16
    const float* __restrict__ bias,         // [N] fp32
    int M, int N, int K, int mode,
    float* __restrict__ outf,
    unsigned short* __restrict__ qb,
    unsigned short* __restrict__ kb,
    unsigned short* __restrict__ vb) {
  __shared__ unsigned short As[128 * 64];
  __shared__ unsigned short Bs[128 * 64];

  const int tid  = threadIdx.x;
  const int lane = tid & 63;
  const int wave = tid >> 6;
  const int quad = lane >> 4;
  const int l16  = lane & 15;
  const int q4   = quad * 4;

  const int bm = blockIdx.y * 128;
  const int bn = blockIdx.x * 128;
  const int wm = (wave >> 1) * 64;
  const int wn = (wave & 1) * 64;

  f32x4 acc[4][4] = {};

  const int srow8 = lane >> 3;                       // row within 8-row group
  const int scol  = ((lane & 7) ^ srow8) * 8;        // swizzled source column
  const int srow  = wave * 8 + srow8;

  for (int k0 = 0; k0 < K; k0 += 64) {
#pragma unroll
    for (int c = 0; c < 4; ++c) {
      const int r = c * 32 + srow;
      const unsigned short* ga = A  + (size_t)(bm + r) * K + (k0 + scol);
      const unsigned short* gb = Bm + (size_t)(bn + r) * K + (k0 + scol);
      unsigned short* la = &As[(c * 32 + wave * 8) * 64];
      unsigned short* lb = &Bs[(c * 32 + wave * 8) * 64];
      __builtin_amdgcn_global_load_lds(
          (__attribute__((address_space(1))) unsigned int*)ga,
          (__attribute__((address_space(3))) unsigned int*)la, 16, 0, 0);
      __builtin_amdgcn_global_load_lds(
          (__attribute__((address_space(1))) unsigned int*)gb,
          (__attribute__((address_space(3))) unsigned int*)lb, 16, 0, 0);
    }
    __syncthreads();
#pragma unroll
    for (int ks = 0; ks < 2; ++ks) {
      bf16x8 af[4], bfr[4];
#pragma unroll
      for (int i = 0; i < 4; ++i)
        af[i] = *(const bf16x8*)&As[(wm + i * 16 + l16) * 64 +
                                    (((ks * 4 + quad) ^ (l16 & 7)) * 8)];
#pragma unroll
      for (int j = 0; j < 4; ++j)
        bfr[j] = *(const bf16x8*)&Bs[(wn + j * 16 + l16) * 64 +
                                     (((ks * 4 + quad) ^ (l16 & 7)) * 8)];
#pragma unroll
      for (int i = 0; i < 4; ++i)
#pragma unroll
        for (int j = 0; j < 4; ++j)
          acc[i][j] = __builtin_amdgcn_mfma_f32_16x16x32_bf16(af[i], bfr[j], acc[i][j], 0, 0, 0);
    }
    __syncthreads();
  }

#pragma unroll
  for (int j = 0; j < 4; ++j) {
    const int gn = bn + wn + j * 16 + l16;
    const float bv = bias[gn];
    if (mode == 0) {
#pragma unroll
      for (int i = 0; i < 4; ++i)
#pragma unroll
        for (int r = 0; r < 4; ++r) {
          const int gm = bm + wm + i * 16 + q4 + r;
          outf[(size_t)gm * N + gn] = acc[i][j][r] + bv;
        }
    } else {
      const int which = gn >> 10;      // 0=q 1=k 2=v
      const int cc = gn & 1023;
      const int h = cc >> 6, d = cc & 63;
      if (which == 2) {
        // V transposed [b,h,d,t]: pack 4 consecutive t into one ushort4
#pragma unroll
        for (int i = 0; i < 4; ++i) {
          const int gm0 = bm + wm + i * 16 + q4;
          const int b = gm0 >> 11, t0 = gm0 & 2047;
          ushort4 u;
          u.x = f2bf(acc[i][j][0] + bv);
          u.y = f2bf(acc[i][j][1] + bv);
          u.z = f2bf(acc[i][j][2] + bv);
          u.w = f2bf(acc[i][j][3] + bv);
          *(ushort4*)&vb[(((size_t)(b * H_ + h) * D_) + d) * T_ + t0] = u;
        }
      } else {
        // Q gets 1/sqrt(64) * log2(e) folded in -> softmax uses bare v_exp_f32
        const float sc = (which == 0) ? 0.18033688011112042f : 1.0f;
        unsigned short* dst = (which == 0) ? qb : kb;
#pragma unroll
        for (int i = 0; i < 4; ++i)
#pragma unroll
          for (int r = 0; r < 4; ++r) {
            const int gm = bm + wm + i * 16 + q4 + r;
            const int b = gm >> 11, t = gm & 2047;
            dst[(((size_t)(b * H_ + h) * T_) + t) * D_ + d] = f2bf((acc[i][j][r] + bv) * sc);
          }
      }
    }
  }
}

// ---------------- proj GEMM: 128x64 tile for occupancy ---------------------
// M=4096 N=1024 K=1024. 128^2 gives only 256 blocks = 1/CU (fully exposed
// barrier/staging latency). BN=64 -> 512 blocks = 2/CU. XCD-chunked bijective
// swizzle: each XCD's 64-block chunk shares the whole 2MB B (L2-resident).
// Same XOR-swizzled LDS pattern as gemm_bt. 4 waves = 2Mx2N of 64x32.
__global__ __launch_bounds__(256) void gemm_proj(
    const unsigned short* __restrict__ A,   // yb  [4096][1024] bf16
    const unsigned short* __restrict__ Bm,  // wpb [1024][1024] bf16
    const float* __restrict__ bias,         // [1024] fp32
    float* __restrict__ outf) {             // [4096][1024] fp32
  __shared__ unsigned short As[128 * 64];
  __shared__ unsigned short Bs[64 * 64];

  const int tid  = threadIdx.x;
  const int lane = tid & 63;
  const int wave = tid >> 6;
  const int quad = lane >> 4;
  const int l16  = lane & 15;
  const int q4   = quad * 4;

  // 512 blocks: nid = xcd-chunked bijective swizzle (512 % 8 == 0)
  const int id0 = blockIdx.x;
  const int nid = (id0 & 7) * 64 + (id0 >> 3);
  const int bm = (nid >> 4) * 128;   // 32 m-tiles
  const int bn = (nid & 15) * 64;    // 16 n-tiles

  const int wm = (wave >> 1) * 64;   // 0,64
  const int wn = (wave & 1) * 32;    // 0,32

  f32x4 acc[4][2] = {};

  const int srow8 = lane >> 3;
  const int scol  = ((lane & 7) ^ srow8) * 8;

  for (int k0 = 0; k0 < 1024; k0 += 64) {
#pragma unroll
    for (int c = 0; c < 4; ++c) {
      const int r = c * 32 + wave * 8 + srow8;
      const unsigned short* ga = A + (size_t)(bm + r) * 1024 + (k0 + scol);
      unsigned short* la = &As[(c * 32 + wave * 8) * 64];
      __builtin_amdgcn_global_load_lds(
          (__attribute__((address_space(1))) unsigned int*)ga,
          (__attribute__((address_space(3))) unsigned int*)la, 16, 0, 0);
    }
#pragma unroll
    for (int c = 0; c < 2; ++c) {
      const int r = c * 32 + wave * 8 + srow8;
      const unsigned short* gb = Bm + (size_t)(bn + r) * 1024 + (k0 + scol);
      unsigned short* lb = &Bs[(c * 32 + wave * 8) * 64];
      __builtin_amdgcn_global_load_lds(
          (__attribute__((address_space(1))) unsigned int*)gb,
          (__attribute__((address_space(3))) unsigned int*)lb, 16, 0, 0);
    }
    __syncthreads();
#pragma unroll
    for (int ks = 0; ks < 2; ++ks) {
      bf16x8 af[4], bfr[2];
#pragma unroll
      for (int i = 0; i < 4; ++i)
        af[i] = *(const bf16x8*)&As[(wm + i * 16 + l16) * 64 +
                                    (((ks * 4 + quad) ^ (l16 & 7)) * 8)];
#pragma unroll
      for (int j = 0; j < 2; ++j)
        bfr[j] = *(const bf16x8*)&Bs[(wn + j * 16 + l16) * 64 +
                                     (((ks * 4 + quad) ^ (l16 & 7)) * 8)];
#pragma unroll
      for (int i = 0; i < 4; ++i)
#pragma unroll
        for (int j = 0; j < 2; ++j)
          acc[i][j] = __builtin_amdgcn_mfma_f32_16x16x32_bf16(af[i], bfr[j], acc[i][j], 0, 0, 0);
    }
    __syncthreads();
  }

#pragma unroll
  for (int j = 0; j < 2; ++j) {
    const int gn = bn + wn + j * 16 + l16;
    const float bv = bias[gn];
#pragma unroll
    for (int i = 0; i < 4; ++i)
#pragma unroll
      for (int r = 0; r < 4; ++r) {
        const int gm = bm + wm + i * 16 + q4 + r;
        outf[(size_t)gm * 1024 + gn] = acc[i][j][r] + bv;
      }
  }
}

// ---------------- MFMA causal flash attention, key-split -------------------
// R1 structure (LDS dbuf K/V, one barrier/tile, fixed-max softmax with log2e
// folded into Q, cvt_pk P-pack, setprio) + XCD-locality grid encoding:
// id = w*32 + bh, so all 40 blocks sharing one head's K/V (512KB, L2-fit)
// have the same id%8 -> same XCD (4 heads x 512KB = 2MB per XCD L2).
// R4 lesson: LDS staging is load-bearing (removing it: 41.6 -> 86us).
__global__ __launch_bounds__(256, 2) void attn_mfma(
    const unsigned short* __restrict__ Qb,
    const unsigned short* __restrict__ Kb,   // [b,h,t,d]
    const unsigned short* __restrict__ Vtg,  // [b,h,d,t]
    unsigned short* __restrict__ Yb,
    unsigned short* __restrict__ op,         // partial O  [1280][128][64] bf16
    float* __restrict__ lp) {                // partial l  [1280][128] fp32
  __shared__ unsigned short Ks[2][64 * 64];  // [key][dim]   (swizzled)
  __shared__ unsigned short Vt[2][64 * 64];  // [dim][key]   (swizzled)
  __shared__ unsigned short Pw[4][32 * 64];  // per-wave [q][key] (swizzled)

  const int tid  = threadIdx.x;
  const int lane = tid & 63;
  const int wave = tid >> 6;
  const int quad = lane >> 4;
  const int l16  = lane & 15;
  const int q4   = quad * 4;
  const int sw   = (l16 & 7);                // swizzle key

  const int id = blockIdx.x;                 // 0..1279 = w*32 + bh
  const int bh = id & 31;                    // same bh -> same id%8 -> same XCD
  const int w  = id >> 5;                    // work item in [0,40)
  int qt, chunk, nsplits;
  if (w < 4)       { qt = w;                 chunk = 0;            nsplits = 1; }
  else if (w < 12) { qt = 4 + ((w - 4) >> 1); chunk = (w - 4) & 1;  nsplits = 2; }
  else if (w < 24) { qt = 8 + (w - 12) / 3;  chunk = (w - 12) % 3; nsplits = 3; }
  else             { qt = 12 + ((w - 24) >> 2); chunk = (w - 24) & 3; nsplits = 4; }

  const int tiles_total = 2 * qt + 2;
  const int tpc = (tiles_total + nsplits - 1) / nsplits;
  const int t0 = chunk * tpc;
  const int t1 = min(t0 + tpc, tiles_total);

  const int b = bh >> 4, h = bh & 15;
  const size_t base = (size_t)bh * T_ * D_;
  const int wq = qt * 128 + wave * 32;       // wave's first global q row
  const int wt1 = min(t1, (wq + 95) >> 6);   // wave's causal tile bound

  // Q fragments (B-operand layout), loaded once from global
  bf16x8 qf[2][2];
#pragma unroll
  for (int nt = 0; nt < 2; ++nt)
#pragma unroll
    for (int ks = 0; ks < 2; ++ks)
      qf[nt][ks] = *(const bf16x8*)(Qb + base + (size_t)(wq + nt * 16 + l16) * 64 +
                                    ks * 32 + quad * 8);

  f32x4 o[4][2] = {};                        // O^T tiles: [d-tile][q-tile]
  float l2[2] = {0.f, 0.f};

  const int srow8 = lane >> 3;
  const int satom = ((lane & 7) ^ srow8) * 8;  // swizzled source column

#define STAGE_KV(KT, BI)                                                       \
  do {                                                                         \
    const int kt0s = (KT) * 64;                                                \
    _Pragma("unroll")                                                          \
    for (int c = 0; c < 2; ++c) {                                              \
      const int row = wave * 16 + c * 8 + srow8;                               \
      const unsigned short* gk = Kb + base + (size_t)(kt0s + row) * 64 + satom;\
      const unsigned short* gv = Vtg + base + (size_t)row * T_ + kt0s + satom; \
      unsigned short* lk = &Ks[BI][(wave * 16 + c * 8) * 64];                  \
      unsigned short* lv = &Vt[BI][(wave * 16 + c * 8) * 64];                  \
      __builtin_amdgcn_global_load_lds(                                        \
          (__attribute__((address_space(1))) unsigned int*)gk,                 \
          (__attribute__((address_space(3))) unsigned int*)lk, 16, 0, 0);      \
      __builtin_amdgcn_global_load_lds(                                        \
          (__attribute__((address_space(1))) unsigned int*)gv,                 \
          (__attribute__((address_space(3))) unsigned int*)lv, 16, 0, 0);      \
    }                                                                          \
  } while (0)

  // prologue: stage first tile into buffer 0
  STAGE_KV(t0, 0);
  int cur = 0;

  for (int kt = t0; kt < t1; ++kt) {
    const int kt0 = kt * 64;
    __syncthreads();                         // buf[cur] loads drained (implicit vmcnt0)
    if (kt + 1 < t1) STAGE_KV(kt + 1, cur ^ 1);  // prefetch next tile under compute

    if (kt < wt1) {                          // wave-uniform causal guard
      // ---- S^T = K Q^T ----
      f32x4 s[4][2] = {};
#pragma unroll
      for (int ks = 0; ks < 2; ++ks) {
        bf16x8 kf[4];
#pragma unroll
        for (int mt = 0; mt < 4; ++mt)
          kf[mt] = *(const bf16x8*)&Ks[cur][(mt * 16 + l16) * 64 +
                                           (((ks * 4 + quad) ^ sw) * 8)];
        __builtin_amdgcn_s_setprio(1);
#pragma unroll
        for (int mt = 0; mt < 4; ++mt)
#pragma unroll
          for (int nt = 0; nt < 2; ++nt)
            s[mt][nt] = __builtin_amdgcn_mfma_f32_16x16x32_bf16(kf[mt], qf[nt][ks],
                                                                s[mt][nt], 0, 0, 0);
        __builtin_amdgcn_s_setprio(0);
      }
      // ---- causal mask (boundary tiles only) ----
      if (kt0 + 63 > wq) {
#pragma unroll
        for (int mt = 0; mt < 4; ++mt)
#pragma unroll
          for (int nt = 0; nt < 2; ++nt)
#pragma unroll
            for (int r = 0; r < 4; ++r)
              if (kt0 + mt * 16 + q4 + r > wq + nt * 16 + l16) s[mt][nt][r] = -1e30f;
      }
      // ---- fixed-max softmax: p = 2^s (log2e pre-folded into Q) ----
#pragma unroll
      for (int nt = 0; nt < 2; ++nt) {
        float ps = 0.f;
#pragma unroll
        for (int mt = 0; mt < 4; ++mt) {
          float p0 = exp2_hw(s[mt][nt][0]);
          float p1 = exp2_hw(s[mt][nt][1]);
          float p2 = exp2_hw(s[mt][nt][2]);
          float p3 = exp2_hw(s[mt][nt][3]);
          ps += (p0 + p1) + (p2 + p3);
          unsigned lo, hi;
          asm("v_cvt_pk_bf16_f32 %0, %1, %2" : "=v"(lo) : "v"(p0), "v"(p1));
          asm("v_cvt_pk_bf16_f32 %0, %1, %2" : "=v"(hi) : "v"(p2), "v"(p3));
          uint2 pk; pk.x = lo; pk.y = hi;
          const int atom = (2 * mt + (quad >> 1)) ^ sw;   // swizzled P atom
          *(uint2*)&Pw[wave][(nt * 16 + l16) * 64 + atom * 8 + (quad & 1) * 4] = pk;
        }
        l2[nt] += ps;
      }
      // ---- O^T += V^T P^T ----
#pragma unroll
      for (int ks = 0; ks < 2; ++ks) {
        bf16x8 vf[4], pf[2];
#pragma unroll
        for (int dt = 0; dt < 4; ++dt)
          vf[dt] = *(const bf16x8*)&Vt[cur][(dt * 16 + l16) * 64 +
                                           (((ks * 4 + quad) ^ sw) * 8)];
#pragma unroll
        for (int nt = 0; nt < 2; ++nt)
          pf[nt] = *(const bf16x8*)&Pw[wave][(nt * 16 + l16) * 64 +
                                            (((ks * 4 + quad) ^ sw) * 8)];
        __builtin_amdgcn_s_setprio(1);
#pragma unroll
        for (int dt = 0; dt < 4; ++dt)
#pragma unroll
          for (int nt = 0; nt < 2; ++nt)
            o[dt][nt] = __builtin_amdgcn_mfma_f32_16x16x32_bf16(vf[dt], pf[nt],
                                                                o[dt][nt], 0, 0, 0);
        __builtin_amdgcn_s_setprio(0);
      }
    }
    cur ^= 1;
  }
#undef STAGE_KV

  // ---- epilogue ----
#pragma unroll
  for (int nt = 0; nt < 2; ++nt) {
    float l = l2[nt];
    l += __shfl_xor(l, 16);
    l += __shfl_xor(l, 32);
    const int qloc = wave * 32 + nt * 16 + l16;
    if (nsplits == 1) {
      const float inv = 1.f / (l + 1e-6f);   // reference denom eps
      const int q = qt * 128 + qloc;
#pragma unroll
      for (int dt = 0; dt < 4; ++dt) {
        ushort4 u;
        u.x = f2bf(o[dt][nt][0] * inv);
        u.y = f2bf(o[dt][nt][1] * inv);
        u.z = f2bf(o[dt][nt][2] * inv);
        u.w = f2bf(o[dt][nt][3] * inv);
        *(ushort4*)&Yb[((size_t)(b * T_ + q)) * C_ + h * 64 + dt * 16 + q4] = u;
      }
    } else {
      // partial write: slot = id = w*32 + bh
      if (quad == 0) lp[(size_t)id * 128 + qloc] = l;
#pragma unroll
      for (int dt = 0; dt < 4; ++dt) {
        ushort4 u;
        u.x = f2bf(o[dt][nt][0]);
        u.y = f2bf(o[dt][nt][1]);
        u.z = f2bf(o[dt][nt][2]);
        u.w = f2bf(o[dt][nt][3]);
        *(ushort4*)&op[(size_t)id * 8192 + (size_t)qloc * 64 + dt * 16 + q4] = u;
      }
    }
  }
}

// ---------------- combine split-K partials -> yb ---------------------------
// Slot layout matches attn's id = w*32 + bh encoding: slot(w,bh) = w*32 + bh.
__global__ __launch_bounds__(256) void attn_combine(
    const unsigned short* __restrict__ op, const float* __restrict__ lp,
    unsigned short* __restrict__ Yb) {
  const int cb = blockIdx.x;                 // 0..383
  const int bh = cb / 12;
  const int qi = cb - bh * 12;
  const int qt = 4 + qi;
  int nsplits, pfx;
  if (qt < 8)       { nsplits = 2; pfx = 4 + 2 * (qt - 4); }
  else if (qt < 12) { nsplits = 3; pfx = 12 + 3 * (qt - 8); }
  else              { nsplits = 4; pfx = 24 + 4 * (qt - 12); }

  const int t = threadIdx.x;
  const int qloc = t >> 1;
  const int d0 = (t & 1) * 32;

  float l = 1e-6f;
  float acc[32];
#pragma unroll
  for (int i = 0; i < 32; ++i) acc[i] = 0.f;
  for (int s = 0; s < nsplits; ++s) {
    const int slot = (pfx + s) * 32 + bh;
    l += lp[(size_t)slot * 128 + qloc];
    const uint4* src = (const uint4*)(op + (size_t)slot * 8192 +
                                      (size_t)qloc * 64 + d0);
#pragma unroll
    for (int c = 0; c < 4; ++c) {
      uint4 v = src[c];
      acc[c*8+0] += __uint_as_float(v.x << 16);
      acc[c*8+1] += __uint_as_float(v.x & 0xffff0000u);
      acc[c*8+2] += __uint_as_float(v.y << 16);
      acc[c*8+3] += __uint_as_float(v.y & 0xffff0000u);
      acc[c*8+4] += __uint_as_float(v.z << 16);
      acc[c*8+5] += __uint_as_float(v.z & 0xffff0000u);
      acc[c*8+6] += __uint_as_float(v.w << 16);
      acc[c*8+7] += __uint_as_float(v.w & 0xffff0000u);
    }
  }
  const float inv = 1.f / l;
  const int b = bh >> 4, h = bh & 15;
  const int q = qt * 128 + qloc;
  uint4* dst = (uint4*)(Yb + ((size_t)(b * T_ + q)) * C_ + h * 64 + d0);
#pragma unroll
  for (int c = 0; c < 4; ++c) {
    uint4 v;
    v.x = (unsigned)f2bf(acc[c*8+0] * inv) | ((unsigned)f2bf(acc[c*8+1] * inv) << 16);
    v.y = (unsigned)f2bf(acc[c*8+2] * inv) | ((unsigned)f2bf(acc[c*8+3] * inv) << 16);
    v.z = (unsigned)f2bf(acc[c*8+4] * inv) | ((unsigned)f2bf(acc[c*8+5] * inv) << 16);
    v.w = (unsigned)f2bf(acc[c*8+6] * inv) | ((unsigned)f2bf(acc[c*8+7] * inv) << 16);
    dst[c] = v;
  }
}

extern "C" void kernel_launch(void* const* d_in, const int* in_sizes, int n_in,
                              void* d_out, int out_size, void* d_ws, size_t ws_size,
                              hipStream_t stream) {
  const float* x      = (const float*)d_in[0];
  const float* w_attn = (const float*)d_in[1];
  const float* b_attn = (const float*)d_in[2];
  const float* w_proj = (const float*)d_in[3];
  const float* b_proj = (const float*)d_in[4];
  float* out = (float*)d_out;

  char* ws = (char*)d_ws;
  unsigned short* xb  = (unsigned short*)ws;  ws += (size_t)4096 * 1024 * 2;
  unsigned short* wab = (unsigned short*)ws;  ws += (size_t)3072 * 1024 * 2;
  unsigned short* wpb = (unsigned short*)ws;  ws += (size_t)1024 * 1024 * 2;
  unsigned short* qb  = (unsigned short*)ws;  ws += (size_t)B_ * H_ * T_ * D_ * 2;
  unsigned short* kb  = (unsigned short*)ws;  ws += (size_t)B_ * H_ * T_ * D_ * 2;
  unsigned short* vb  = (unsigned short*)ws;  ws += (size_t)B_ * H_ * T_ * D_ * 2;  // [b,h,d,t]
  unsigned short* yb  = (unsigned short*)ws;  ws += (size_t)4096 * 1024 * 2;
  unsigned short* op  = (unsigned short*)ws;  ws += (size_t)1280 * 128 * 64 * 2;    // partial O
  float*          lp  = (float*)ws;           ws += (size_t)1280 * 128 * 4;         // partial l
  (void)ws_size; (void)in_sizes; (void)n_in; (void)out_size;

  convert_all<<<8192, 256, 0, stream>>>(x, w_attn, w_proj, xb, wab, wpb);

  // QKV: [4096,1024] @ [3072,1024]^T + b_attn -> bf16 Q(scaled)/K [B,H,T,D], V [B,H,D,T]
  gemm_bt<<<dim3(24, 32), 256, 0, stream>>>(xb, wab, b_attn, 4096, 3072, 1024, 1,
                                            nullptr, qb, kb, vb);
  // key-split MFMA causal flash attention (XCD-local bh grouping)
  attn_mfma<<<1280, 256, 0, stream>>>(qb, kb, vb, yb, op, lp);
  attn_combine<<<384, 256, 0, stream>>>(op, lp, yb);
  // proj: [4096,1024] @ [1024,1024]^T + b_proj -> fp32 out, 128x64 tile 2/CU
  gemm_proj<<<512, 256, 0, stream>>>(yb, wpb, b_proj, out);
}